// Round 2
// 404.529 us; speedup vs baseline: 1.0025x; 1.0025x over previous
//
#include <hip/hip_runtime.h>
#include <cmath>

#define TOKENS 16384
#define DM     4096
#define NEXP   64
#define S_W    64.0f     // wg pre-scale (keeps wh out of half-denormal range)
#define S_LO   2048.0f   // lo-channel scale (keeps xl/wl normal halves)

typedef _Float16 half8  __attribute__((ext_vector_type(8)));
typedef __fp16   h2rtz  __attribute__((ext_vector_type(2)));   // cvt_pkrtz result type
typedef float    f32x4  __attribute__((ext_vector_type(4)));

// ws layout: whB[262144] halves | wlB[262144] halves | gsum[128] f32 (imp|cnt) | done-counter u32

// ---------- Kernel P: wg -> B-fragment-ordered fp16 hi/lo + zero gsum -------
// block = (kb, et); lane holds B[k=8*(lane>>4)+j][n=(lane&15)] for j=0..7.
__global__ __launch_bounds__(64)
void prep_kernel(const float* __restrict__ wg, _Float16* __restrict__ whB,
                 _Float16* __restrict__ wlB, float* __restrict__ gsum)
{
    const int kb = blockIdx.x >> 2;
    const int et = blockIdx.x & 3;
    const int l  = threadIdx.x;
    const int e  = et * 16 + (l & 15);
    const int k0 = kb * 32 + 8 * (l >> 4);

    const float* wp = wg + (size_t)e * DM + k0;
    float v[8];
    *(f32x4*)(v)     = *(const f32x4*)(wp);
    *(f32x4*)(v + 4) = *(const f32x4*)(wp + 4);

    half8 hh, ll;
    #pragma unroll
    for (int j = 0; j < 8; ++j) {
        const float ws = v[j] * S_W;
        const _Float16 h = (_Float16)ws;
        hh[j] = h;
        ll[j] = (_Float16)((ws - (float)h) * S_LO);
    }
    const int idx = blockIdx.x * 64 + l;   // (kb*4+et)*64 + lane
    ((half8*)whB)[idx] = hh;
    ((half8*)wlB)[idx] = ll;

    if (blockIdx.x == 0) {
        gsum[l] = 0.f; gsum[64 + l] = 0.f;
        if (l == 0) *(unsigned*)(gsum + 128) = 0u;
    }
}

// packed fp32 -> (hi fp16, lo fp16*S_LO) split, RTZ hi + exact residual
__device__ __forceinline__ void split8(const f32x4& a0, const f32x4& a1,
                                       half8& xh, half8& xl)
{
    float v[8];
    *(f32x4*)(v)     = a0;
    *(f32x4*)(v + 4) = a1;
    h2rtz h01 = __builtin_amdgcn_cvt_pkrtz(v[0], v[1]);
    h2rtz h23 = __builtin_amdgcn_cvt_pkrtz(v[2], v[3]);
    h2rtz h45 = __builtin_amdgcn_cvt_pkrtz(v[4], v[5]);
    h2rtz h67 = __builtin_amdgcn_cvt_pkrtz(v[6], v[7]);
    xh[0] = (_Float16)h01[0]; xh[1] = (_Float16)h01[1];
    xh[2] = (_Float16)h23[0]; xh[3] = (_Float16)h23[1];
    xh[4] = (_Float16)h45[0]; xh[5] = (_Float16)h45[1];
    xh[6] = (_Float16)h67[0]; xh[7] = (_Float16)h67[1];
    const float r0 = (v[0] - (float)h01[0]) * S_LO;
    const float r1 = (v[1] - (float)h01[1]) * S_LO;
    const float r2 = (v[2] - (float)h23[0]) * S_LO;
    const float r3 = (v[3] - (float)h23[1]) * S_LO;
    const float r4 = (v[4] - (float)h45[0]) * S_LO;
    const float r5 = (v[5] - (float)h45[1]) * S_LO;
    const float r6 = (v[6] - (float)h67[0]) * S_LO;
    const float r7 = (v[7] - (float)h67[1]) * S_LO;
    h2rtz l01 = __builtin_amdgcn_cvt_pkrtz(r0, r1);
    h2rtz l23 = __builtin_amdgcn_cvt_pkrtz(r2, r3);
    h2rtz l45 = __builtin_amdgcn_cvt_pkrtz(r4, r5);
    h2rtz l67 = __builtin_amdgcn_cvt_pkrtz(r6, r7);
    xl[0] = (_Float16)l01[0]; xl[1] = (_Float16)l01[1];
    xl[2] = (_Float16)l23[0]; xl[3] = (_Float16)l23[1];
    xl[4] = (_Float16)l45[0]; xl[5] = (_Float16)l45[1];
    xl[6] = (_Float16)l67[0]; xl[7] = (_Float16)l67[1];
}

// ---------- Kernel M: fp16-split MFMA logits + fused gate + fused aux -------
// 512 blocks x 256 thr (4 waves): wave = (tgrp in [0,2)) + 2*(khalf in [0,2)).
// Each wave: 16 tokens x 64 experts over half of K. LDS merge of k-halves,
// then khalf==0 waves do softmax/top-2/partials. Last block computes aux.
__global__ __launch_bounds__(256, 2)
void moe_kernel(const float* __restrict__ x, const _Float16* __restrict__ whB,
                const _Float16* __restrict__ wlB, float* __restrict__ out,
                float* __restrict__ gsum)
{
    const int lane  = threadIdx.x & 63;
    const int wave  = threadIdx.x >> 6;
    const int tgrp  = wave & 1;
    const int khalf = wave >> 1;
    const int sub   = lane & 15;
    const int q     = lane >> 4;
    const int t0    = blockIdx.x * 32 + tgrp * 16;

    f32x4 ahh[4] = {};
    f32x4 amd[4] = {};

    // A-frag natural global read: lane -> (token t0+sub, k = kb*32 + 8q + j)
    const float* xp = x + (size_t)(t0 + sub) * DM + 8 * q;
    const half8* whv = (const half8*)whB;
    const half8* wlv = (const half8*)wlB;

    const int kb0 = khalf * 64, kbe = kb0 + 64;

    // ---- 4-slot A ring, 3 iterations of HBM loads in flight ----
    f32x4 ra0[4], ra1[4];
    #pragma unroll
    for (int d = 0; d < 3; ++d) {
        ra0[d] = __builtin_nontemporal_load((const f32x4*)(xp + (kb0 + d) * 32));
        ra1[d] = __builtin_nontemporal_load((const f32x4*)(xp + (kb0 + d) * 32 + 4));
    }

    // ---- B double buffer (L2-resident), 1 iteration ahead ----
    half8 bh[2][4], bl[2][4];
    #pragma unroll
    for (int et = 0; et < 4; ++et) {
        bh[0][et] = whv[kb0 * 256 + lane + et * 64];
        bl[0][et] = wlv[kb0 * 256 + lane + et * 64];
    }

    for (int kb = kb0; kb < kbe; kb += 4) {
        #pragma unroll
        for (int u = 0; u < 4; ++u) {
            const int k = kb + u;

            // issue A loads for k+3 (slot (u+3)&3 is static under unroll)
            const int kpf = (k + 3 < kbe) ? k + 3 : kbe - 1;
            ra0[(u + 3) & 3] = __builtin_nontemporal_load((const f32x4*)(xp + kpf * 32));
            ra1[(u + 3) & 3] = __builtin_nontemporal_load((const f32x4*)(xp + kpf * 32 + 4));

            // issue B loads for k+1 into the other buffer
            const int knb = (k + 1 < kbe) ? k + 1 : kbe - 1;
            const int cur = u & 1, nxt = cur ^ 1;
            #pragma unroll
            for (int et = 0; et < 4; ++et) {
                bh[nxt][et] = whv[knb * 256 + lane + et * 64];
                bl[nxt][et] = wlv[knb * 256 + lane + et * 64];
            }

            // convert current A slot and accumulate
            half8 xh, xl;
            split8(ra0[u], ra1[u], xh, xl);

            #pragma unroll
            for (int et = 0; et < 4; ++et) {
                ahh[et] = __builtin_amdgcn_mfma_f32_16x16x32_f16(xh, bh[cur][et], ahh[et], 0, 0, 0);
                amd[et] = __builtin_amdgcn_mfma_f32_16x16x32_f16(xh, bl[cur][et], amd[et], 0, 0, 0);
                amd[et] = __builtin_amdgcn_mfma_f32_16x16x32_f16(xl, bh[cur][et], amd[et], 0, 0, 0);
            }
        }
    }

    // logits = (hh + mid/2048) / 64 ; C/D: expert = sub+16*et, token = 4q+reg
    float lg[4][4];
    #pragma unroll
    for (int et = 0; et < 4; ++et)
        #pragma unroll
        for (int r = 0; r < 4; ++r)
            lg[et][r] = (ahh[et][r] + amd[et][r] * (1.0f / S_LO)) * (1.0f / S_W);

    __shared__ float lmerge[2][16][64];
    __shared__ float bimp[2][64], bcnt[2][64];

    if (khalf == 1) {
        #pragma unroll
        for (int et = 0; et < 4; ++et)
            #pragma unroll
            for (int r = 0; r < 4; ++r)
                lmerge[tgrp][4 * q + r][sub + 16 * et] = lg[et][r];
    }
    __syncthreads();

    if (khalf == 0) {
        float imp[4] = {0, 0, 0, 0}, cnt[4] = {0, 0, 0, 0};
        #pragma unroll
        for (int et = 0; et < 4; ++et)
            #pragma unroll
            for (int r = 0; r < 4; ++r)
                lg[et][r] += lmerge[tgrp][4 * q + r][sub + 16 * et];

        for (int r = 0; r < 4; ++r) {
            const int tok = t0 + 4 * q + r;
            float m = fmaxf(fmaxf(lg[0][r], lg[1][r]), fmaxf(lg[2][r], lg[3][r]));
            #pragma unroll
            for (int off = 1; off < 16; off <<= 1) m = fmaxf(m, __shfl_xor(m, off));
            float p[4]; float s = 0.f;
            #pragma unroll
            for (int et = 0; et < 4; ++et) { p[et] = expf(lg[et][r] - m); s += p[et]; }
            #pragma unroll
            for (int off = 1; off < 16; off <<= 1) s += __shfl_xor(s, off);
            #pragma unroll
            for (int et = 0; et < 4; ++et) p[et] = p[et] / s;

            // local top-2 (ties -> lower index; ids increase with et)
            float v1, v2; int i1, i2;
            if (p[1] > p[0]) { v1 = p[1]; i1 = sub + 16; v2 = p[0]; i2 = sub; }
            else             { v1 = p[0]; i1 = sub;      v2 = p[1]; i2 = sub + 16; }
            #pragma unroll
            for (int et = 2; et < 4; ++et) {
                const float vv = p[et]; const int id = sub + 16 * et;
                if (vv > v1)      { v2 = v1; i2 = i1; v1 = vv; i1 = id; }
                else if (vv > v2) { v2 = vv; i2 = id; }
            }
            // cross-lane merge within the 16-lane token group
            #pragma unroll
            for (int off = 1; off < 16; off <<= 1) {
                const float w1 = __shfl_xor(v1, off), w2 = __shfl_xor(v2, off);
                const int   j1 = __shfl_xor(i1, off), j2 = __shfl_xor(i2, off);
                if (w1 > v1 || (w1 == v1 && j1 < i1)) {
                    if (v1 > w2 || (v1 == w2 && i1 < j2)) { v2 = v1; i2 = i1; }
                    else                                   { v2 = w2; i2 = j2; }
                    v1 = w1; i1 = j1;
                } else {
                    if (w1 > v2 || (w1 == v2 && j1 < i2)) { v2 = w1; i2 = j1; }
                }
            }

            if (sub == 0) {
                out[2 * tok]                  = (float)i1;
                out[2 * tok + 1]              = (float)i2;
                out[2 * TOKENS + 2 * tok]     = v1;
                out[2 * TOKENS + 2 * tok + 1] = v2;
            }
            #pragma unroll
            for (int et = 0; et < 4; ++et) {
                imp[et] += p[et];
                if (i1 == sub + 16 * et) cnt[et] += 1.0f;
            }
        }
        #pragma unroll
        for (int et = 0; et < 4; ++et) {
            imp[et] += __shfl_xor(imp[et], 16); imp[et] += __shfl_xor(imp[et], 32);
            cnt[et] += __shfl_xor(cnt[et], 16); cnt[et] += __shfl_xor(cnt[et], 32);
        }
        if (q == 0) {
            #pragma unroll
            for (int et = 0; et < 4; ++et) {
                bimp[tgrp][sub + 16 * et] = imp[et];
                bcnt[tgrp][sub + 16 * et] = cnt[et];
            }
        }
    }
    __syncthreads();

    if (wave == 0) {
        atomicAdd(gsum + lane,      bimp[0][lane] + bimp[1][lane]);
        atomicAdd(gsum + 64 + lane, bcnt[0][lane] + bcnt[1][lane]);
        __threadfence();
        int last = 0;
        if (lane == 0) {
            unsigned old = atomicAdd((unsigned*)(gsum + 128), 1u);
            last = (old == 511u);
        }
        last = __shfl(last, 0);
        if (last) {
            __threadfence();
            // read via atomic RMW (device-scope coherent across XCDs)
            const float a = atomicAdd(gsum + lane, 0.f);
            const float b = atomicAdd(gsum + 64 + lane, 0.f);
            float prod = a * b;
            #pragma unroll
            for (int off = 32; off; off >>= 1) prod += __shfl_xor(prod, off);
            if (lane == 0)
                out[4 * TOKENS] = (float)NEXP * prod / ((float)TOKENS * (float)TOKENS);
        }
    }
}

extern "C" void kernel_launch(void* const* d_in, const int* in_sizes, int n_in,
                              void* d_out, int out_size, void* d_ws, size_t ws_size,
                              hipStream_t stream) {
    const float* x  = (const float*)d_in[0];
    const float* wg = (const float*)d_in[1];
    float* out = (float*)d_out;

    _Float16* whB = (_Float16*)d_ws;            // 512 KB
    _Float16* wlB = whB + 262144;               // 512 KB
    float*    gsum = (float*)(wlB + 262144);    // 128 floats: imp | cnt, + done counter

    prep_kernel<<<512, 64, 0, stream>>>(wg, whB, wlB, gsum);
    moe_kernel<<<512, 256, 0, stream>>>(x, whB, wlB, out, gsum);
}